// Round 2
// baseline (660.209 us; speedup 1.0000x reference)
//
#include <hip/hip_runtime.h>

#define NH   4
#define ATT  16
#define COL  64
#define AIS  64
#define SK   200
#define HD   64
#define JP   32          // j-pairs per row
#define AROW 33          // uint (half2) stride per k row: bank=(k+jp)%32 -> 2-way free
#define NBPB 16          // batches per persistent block

typedef _Float16 half2v __attribute__((ext_vector_type(2)));
typedef unsigned int uint32;

static __device__ __forceinline__ half2v u2h(uint32 u) {
    union { uint32 u; half2v h; } x; x.u = u; return x.h;
}

// pack two f32 -> f16x2 as raw uint32
static __device__ __forceinline__ uint32 pk_u32(float a, float b) {
#if __has_builtin(__builtin_amdgcn_cvt_pkrtz)
    union { decltype(__builtin_amdgcn_cvt_pkrtz(0.f, 0.f)) h; uint32 u; } x;
    x.h = __builtin_amdgcn_cvt_pkrtz(a, b);
    return x.u;
#else
    union { half2v h; uint32 u; } x;
    x.h.x = (_Float16)a; x.h.y = (_Float16)b;
    return x.u;
#endif
}

#if __has_builtin(__builtin_amdgcn_fdot2)
#define DOT2(a, b, c) __builtin_amdgcn_fdot2((a), (b), (c), false)
#else
#define DOT2(a, b, c) fmaf((float)(a).x, (float)(b).x, fmaf((float)(a).y, (float)(b).y, (c)))
#endif

// Raw workgroup barrier: waits only LDS (lgkmcnt), NOT vmcnt -> in-flight
// global loads survive across it (the whole point of the pipeline).
static __device__ __forceinline__ void wg_barrier() {
    asm volatile("s_waitcnt lgkmcnt(0)" ::: "memory");
    __builtin_amdgcn_s_barrier();
    asm volatile("" ::: "memory");
}

static __device__ __forceinline__ void issue_loads(float4* sv,
                                                   const float* __restrict__ action,
                                                   size_t b, int t) {
    const float4* a4 = (const float4*)(action + b * (size_t)(SK * AIS));
    #pragma unroll
    for (int j = 0; j < 12; ++j) sv[j] = a4[j * 256 + t];
    if (t < 128) sv[12] = a4[3072 + t];
}

static __device__ __forceinline__ void convert_store(uint32* __restrict__ dst,
                                                     const float4* sv, int t) {
    #pragma unroll
    for (int j = 0; j < 12; ++j) {
        const int idx = j * 256 + t;                 // float4 index
        const float4 v = sv[j];
        const int k   = idx >> 4;                    // 16 float4 per row
        const int jp0 = (idx & 15) * 2;
        dst[k * AROW + jp0]     = pk_u32(v.x, v.y);
        dst[k * AROW + jp0 + 1] = pk_u32(v.z, v.w);
    }
    if (t < 128) {
        const int idx = 3072 + t;
        const float4 v = sv[12];
        const int k   = idx >> 4;
        const int jp0 = (idx & 15) * 2;
        dst[k * AROW + jp0]     = pk_u32(v.x, v.y);
        dst[k * AROW + jp0 + 1] = pk_u32(v.z, v.w);
    }
}

// ---------------------------------------------------------------------------
// Persistent pipelined kernel: 512 blocks x 16 batches, 2 blocks/CU.
//  prologue: qh+qk for all 16 batches -> LDS; A(batch0) -> A2[0]
//  per iter: issue A(i+1) loads -> regs (fly across raw barriers)
//            scores(i) | softmax(i) | w(i) from A2[cur]
//            convert regs -> A2[cur^1]; wave0: reduce+epilogue -> out
// LDS: 52800 (A2 dbuf) + 8192 (qk_all) + 7296 (p4/wpart U qh_all) + 16
//    = 68304 B -> 2 blocks/CU. VGPR budget 256 (launch_bounds 256,2): no spill.
// ---------------------------------------------------------------------------
__global__ __launch_bounds__(256, 2)
void fused_attn_persistent(const float* __restrict__ query,
                           const float* __restrict__ action,
                           const float* __restrict__ Qw,
                           const float* __restrict__ Kw,
                           const float* __restrict__ Vw,
                           float* __restrict__ out, int nbatch) {
    __shared__ uint32 A2[2][SK * AROW];                  // 52800 B
    __shared__ __align__(16) uint32 qk_all[NBPB * JP * NH]; // 8192 B
    union RunLDS {
        float qh_all[NBPB][HD];                          // prologue only (4096)
        struct { float4 p4[SK]; float4 wpart[4][64]; } r; // 3200 + 4096
    };
    __shared__ RunLDS u;
    __shared__ float invd[NH];

    const int t    = threadIdx.x;
    const int lane = t & 63;
    const int wv   = t >> 6;
    const int b0   = blockIdx.x * NBPB;
    if (b0 >= nbatch) return;

    float4 sv[13];

    // ---------------- prologue ----------------
    issue_loads(sv, action, (size_t)b0, t);

    // qh for all NBPB batches: pass p -> batch p*4+wv (wave-uniform row)
    #pragma unroll
    for (int p = 0; p < 4; ++p) {
        const int bi = p * 4 + wv;
        const int b  = b0 + bi;
        float acc = 0.f;
        if (b < nbatch) {
            const float4* qb4 = (const float4*)(query + (size_t)b * COL);
            #pragma unroll
            for (int c4 = 0; c4 < 16; ++c4) {
                const float4 qv = qb4[c4];
                acc = fmaf(qv.x, Qw[(4 * c4 + 0) * HD + lane], acc);
                acc = fmaf(qv.y, Qw[(4 * c4 + 1) * HD + lane], acc);
                acc = fmaf(qv.z, Qw[(4 * c4 + 2) * HD + lane], acc);
                acc = fmaf(qv.w, Qw[(4 * c4 + 3) * HD + lane], acc);
            }
        }
        u.qh_all[bi][lane] = acc;
    }
    __syncthreads();

    // qk for all NBPB batches: 8 passes x 256 threads = 16*128 items
    #pragma unroll
    for (int p = 0; p < 8; ++p) {
        const int item = p * 256 + t;
        const int bi   = item >> 7;
        const int r    = item & 127;
        const int h    = r >> 5;
        const int jp   = r & 31;
        float a0 = 0.f, a1 = 0.f;
        #pragma unroll
        for (int d = 0; d < ATT; ++d) {
            const float q = u.qh_all[bi][h * ATT + d];
            a0 = fmaf(q, Kw[(2 * jp)     * HD + h * ATT + d], a0);
            a1 = fmaf(q, Kw[(2 * jp + 1) * HD + h * ATT + d], a1);
        }
        qk_all[(bi * JP + jp) * 4 + h] = pk_u32(a0 * 0.125f, a1 * 0.125f);
    }

    convert_store(&A2[0][0], sv, t);       // batch 0 -> buffer 0
    __syncthreads();                       // prologue end (one-time full drain)

    // ---------------- main loop ----------------
    int cur = 0;
    for (int i = 0; i < NBPB; ++i) {
        const int  b    = b0 + i;
        const bool live = (b < nbatch);
        const bool pre  = (i + 1 < NBPB) && (b + 1 < nbatch);

        // issue next batch's loads; they stay in flight across raw barriers
        if (pre) issue_loads(sv, action, (size_t)(b + 1), t);

        // ---- scores: thread t = key k ----
        if (live && t < SK) {
            const uint32* Ab  = &A2[cur][t * AROW];
            const uint4*  qk4 = (const uint4*)&qk_all[i * JP * 4];
            float a0 = 0.f, a1 = 0.f, a2 = 0.f, a3 = 0.f;
            #pragma unroll 8
            for (int jp = 0; jp < JP; ++jp) {
                const half2v av = u2h(Ab[jp]);       // bank (k+jp)%32: free
                const uint4  q4 = qk4[jp];           // uniform b128 broadcast
                a0 = DOT2(av, u2h(q4.x), a0);
                a1 = DOT2(av, u2h(q4.y), a1);
                a2 = DOT2(av, u2h(q4.z), a2);
                a3 = DOT2(av, u2h(q4.w), a3);
            }
            float4 s; s.x = a0; s.y = a1; s.z = a2; s.w = a3;
            u.r.p4[t] = s;
        }
        wg_barrier();

        // ---- softmax: wave wv owns head wv; 200 = 3*64 + 8 ----
        if (live) {
            float* pf = (float*)u.r.p4;
            const int h = wv;
            const float s0 = pf[lane * 4 + h];
            const float s1 = pf[(lane + 64) * 4 + h];
            const float s2 = pf[(lane + 128) * 4 + h];
            const float s3 = (lane < SK - 192) ? pf[(lane + 192) * 4 + h] : -1e30f;
            float m = fmaxf(fmaxf(s0, s1), fmaxf(s2, s3));
            #pragma unroll
            for (int off = 32; off; off >>= 1) m = fmaxf(m, __shfl_xor(m, off));
            const float e0 = __expf(s0 - m);
            const float e1 = __expf(s1 - m);
            const float e2 = __expf(s2 - m);
            const float e3 = (lane < SK - 192) ? __expf(s3 - m) : 0.f;
            pf[lane * 4 + h]         = e0;
            pf[(lane + 64) * 4 + h]  = e1;
            pf[(lane + 128) * 4 + h] = e2;
            if (lane < SK - 192) pf[(lane + 192) * 4 + h] = e3;
            float sum = e0 + e1 + e2 + e3;
            #pragma unroll
            for (int off = 32; off; off >>= 1) sum += __shfl_xor(sum, off);
            if (lane == 0) invd[h] = 1.f / sum;
        }
        wg_barrier();

        // ---- w[h][j] = sum_k p[h][k]*A[k][j]; k split across 4 waves ----
        if (live) {
            const int j  = lane;
            const int jp = j >> 1;
            const int k0 = wv * 50;
            float c0 = 0.f, c1 = 0.f, c2 = 0.f, c3 = 0.f;
            #pragma unroll 10
            for (int kk = 0; kk < 50; ++kk) {
                const int k = k0 + kk;
                const float4 p  = u.r.p4[k];                 // uniform b128
                const half2v av = u2h(A2[cur][k * AROW + jp]); // 2-lane bcast
                const float a = (j & 1) ? (float)av.y : (float)av.x;
                c0 = fmaf(p.x, a, c0);
                c1 = fmaf(p.y, a, c1);
                c2 = fmaf(p.z, a, c2);
                c3 = fmaf(p.w, a, c3);
            }
            float4 c; c.x = c0; c.y = c1; c.z = c2; c.w = c3;
            u.r.wpart[wv][j] = c;
        }
        wg_barrier();

        // ---- wave0: reduce + epilogue (no sv dependency -> runs first) ----
        if (live && t < 64) {
            const float4 r0 = u.r.wpart[0][t], r1 = u.r.wpart[1][t];
            const float4 r2 = u.r.wpart[2][t], r3 = u.r.wpart[3][t];
            float4 w;
            w.x = (r0.x + r1.x + r2.x + r3.x) * invd[0];
            w.y = (r0.y + r1.y + r2.y + r3.y) * invd[1];
            w.z = (r0.z + r1.z + r2.z + r3.z) * invd[2];
            w.w = (r0.w + r1.w + r2.w + r3.w) * invd[3];
            u.r.p4[t] = w;                       // w4 aliased onto dead p4
            const int h = t >> 4;
            const float* wf = (const float*)u.r.p4;   // same-wave LDS order
            float acc = 0.f;
            #pragma unroll
            for (int j = 0; j < AIS; ++j)
                acc = fmaf(wf[j * 4 + h], Vw[j * HD + t], acc);
            out[(size_t)b * HD + t] = acc;
        }

        // ---- convert landed regs -> other buffer (vmcnt waited here only) ----
        if (pre) convert_store(&A2[cur ^ 1][0], sv, t);

        wg_barrier();                            // A2[cur^1] + p4 reuse fence
        cur ^= 1;
    }
}

// ---------------------------------------------------------------------------
extern "C" void kernel_launch(void* const* d_in, const int* in_sizes, int n_in,
                              void* d_out, int out_size, void* d_ws, size_t ws_size,
                              hipStream_t stream) {
    const float* query  = (const float*)d_in[0];   // [B,1,64]
    const float* action = (const float*)d_in[1];   // [B,200,64]
    const float* Qw     = (const float*)d_in[2];   // [64,64]
    const float* Kw     = (const float*)d_in[3];   // [64,64]
    const float* Vw     = (const float*)d_in[4];   // [64,64]
    float* outp = (float*)d_out;                   // [B,64]

    (void)d_ws; (void)ws_size;                     // workspace unused

    const int B = in_sizes[0] / COL;               // 8192
    const int nblk = (B + NBPB - 1) / NBPB;        // 512 -> 2 blocks/CU
    fused_attn_persistent<<<nblk, 256, 0, stream>>>(query, action, Qw, Kw, Vw,
                                                    outp, B);
}